// Round 2
// baseline (534.811 us; speedup 1.0000x reference)
//
#include <hip/hip_runtime.h>
#include <hip/hip_bf16.h>
#include <stdint.h>

typedef __hip_bfloat16 bf16;
typedef __attribute__((ext_vector_type(8))) short short8;
typedef __attribute__((ext_vector_type(4))) float f32x4;

#define NTOK  4096      // B*T
#define EDIM  1024
#define NEXPT 8
#define INTERD 1408
#define MAXP  4096
#define WELEM (NEXPT * INTERD * EDIM)

// async global->LDS, 16B per lane, dest = wave-uniform base + lane*16
#define GL16(g, l) __builtin_amdgcn_global_load_lds( \
    (const __attribute__((address_space(1))) unsigned int*)(g), \
    (__attribute__((address_space(3))) unsigned int*)(l), 16, 0, 0)

// ---------------- fused fp32 -> bf16 conversion for all 4 tensors ----------------
__global__ __launch_bounds__(256) void cvt4_kernel(const float* __restrict__ x,  bf16* __restrict__ xb,
                                                   const float* __restrict__ wg, bf16* __restrict__ wgb,
                                                   const float* __restrict__ wu, bf16* __restrict__ wub,
                                                   const float* __restrict__ wd, bf16* __restrict__ wdb) {
    const float* src; bf16* dst; int n, b = blockIdx.x, nb;
    if (b < 512)       { src = x;  dst = xb;  n = NTOK * EDIM; nb = 512; }
    else if (b < 1536) { src = wg; dst = wgb; n = WELEM; b -= 512;  nb = 1024; }
    else if (b < 2560) { src = wu; dst = wub; n = WELEM; b -= 1536; nb = 1024; }
    else               { src = wd; dst = wdb; n = WELEM; b -= 2560; nb = 1024; }
    int i = (b * 256 + threadIdx.x) * 4;
    int stride = nb * 256 * 4;
    for (; i < n; i += stride) {
        float4 v = *(const float4*)(src + i);
        ushort4 o; bf16 t;
        t = __float2bfloat16(v.x); o.x = *(unsigned short*)&t;
        t = __float2bfloat16(v.y); o.y = *(unsigned short*)&t;
        t = __float2bfloat16(v.z); o.z = *(unsigned short*)&t;
        t = __float2bfloat16(v.w); o.w = *(unsigned short*)&t;
        *(ushort4*)(dst + i) = o;
    }
}

// ---------------- router: top2 softmax, bucket scatter + inverse map ----------------
__global__ __launch_bounds__(64) void router_kernel(const float* __restrict__ x,
                                                    const float* __restrict__ gw,
                                                    int* __restrict__ counts,
                                                    int* __restrict__ ptok,
                                                    float* __restrict__ pprob,
                                                    int* __restrict__ inv) {
    int t = blockIdx.x;
    int lane = threadIdx.x;
    const float* xr = x + (size_t)t * EDIM;
    double acc[NEXPT];
#pragma unroll
    for (int e = 0; e < NEXPT; e++) acc[e] = 0.0;
    for (int d = lane; d < EDIM; d += 64) {
        float xv = xr[d];
#pragma unroll
        for (int e = 0; e < NEXPT; e++) acc[e] += (double)xv * (double)gw[e * EDIM + d];
    }
#pragma unroll
    for (int off = 32; off >= 1; off >>= 1) {
#pragma unroll
        for (int e = 0; e < NEXPT; e++) acc[e] += __shfl_xor(acc[e], off, 64);
    }
    if (lane == 0) {
        int e0 = 0; double s0 = acc[0];
        for (int e = 1; e < NEXPT; e++) if (acc[e] > s0) { s0 = acc[e]; e0 = e; }
        int e1 = -1; double s1 = -1e300;
        for (int e = 0; e < NEXPT; e++) if (e != e0 && acc[e] > s1) { s1 = acc[e]; e1 = e; }
        float z = __expf((float)(s1 - s0));
        float p0 = 1.f / (1.f + z);
        float p1 = 1.f - p0;
        int pos0 = atomicAdd(&counts[e0], 1);
        ptok[e0 * MAXP + pos0] = t; pprob[e0 * MAXP + pos0] = p0;
        int pos1 = atomicAdd(&counts[e1], 1);
        ptok[e1 * MAXP + pos1] = t; pprob[e1 * MAXP + pos1] = p1;
        inv[2 * t]     = (e0 << 16) | pos0;
        inv[2 * t + 1] = (e1 << 16) | pos1;
    }
}

__global__ void scan_kernel(const int* __restrict__ counts, int* __restrict__ offsets) {
    if (threadIdx.x == 0 && blockIdx.x == 0) {
        int s = 0;
        for (int e = 0; e < NEXPT; e++) { offsets[e] = s; s += counts[e]; }
    }
}

// ---------------- GEMM1: h = p * silu(x@wg^T) * (x@wu^T), 128tok x 64inter x {g,u} ----
__global__ __launch_bounds__(256) void gemm1_kernel(const bf16* __restrict__ xb,
                                                    const bf16* __restrict__ wgb,
                                                    const bf16* __restrict__ wub,
                                                    bf16* __restrict__ hout,
                                                    const int* __restrict__ counts,
                                                    const int* __restrict__ offsets,
                                                    const int* __restrict__ ptok,
                                                    const float* __restrict__ pprob) {
    int e = blockIdx.x >> 5;          // 32 m-tiles per expert (MAXP/128)
    int mt = blockIdx.x & 31;
    int cnt = counts[e];
    int m0 = mt * 128;
    if (m0 >= cnt) return;
    int n0 = blockIdx.y * 64;         // over INTER (22 tiles)

    __shared__ __align__(16) bf16 sA[128 * 32];
    __shared__ __align__(16) bf16 sBg[64 * 32];
    __shared__ __align__(16) bf16 sBu[64 * 32];

    int tid = threadIdx.x;
    int lane = tid & 63;
    int wid = tid >> 6;
    int wm = wid >> 1, wn = wid & 1;  // wave tile: 64 tok x 32 inter

    // staging geometry: 1KB chunk per wave per issue; row = 16*c_hi + (lane>>2), ch = lane&3
    int sr = lane >> 2;               // 0..15
    int ch = lane & 3;                // 16B chunk within 64B row
    int ra0 = wid * 16 + sr;          // A issue0 rows 0..63
    int ra1 = 64 + ra0;               // A issue1 rows 64..127
    int ta0 = ptok[e * MAXP + min(m0 + ra0, cnt - 1)];
    int ta1 = ptok[e * MAXP + min(m0 + ra1, cnt - 1)];
    const bf16* gA0 = xb + (size_t)ta0 * EDIM + ch * 8;
    const bf16* gA1 = xb + (size_t)ta1 * EDIM + ch * 8;
    int rb = wid * 16 + sr;           // B rows 0..63
    const bf16* gG = wgb + ((size_t)e * INTERD + n0 + rb) * EDIM + ch * 8;
    const bf16* gU = wub + ((size_t)e * INTERD + n0 + rb) * EDIM + ch * 8;
    bf16* dA0 = sA  + wid * 512;
    bf16* dA1 = sA  + (4 + wid) * 512;
    bf16* dG  = sBg + wid * 512;
    bf16* dU  = sBu + wid * 512;

    f32x4 accg[4][2], accu[4][2];
#pragma unroll
    for (int m = 0; m < 4; m++)
#pragma unroll
        for (int n = 0; n < 2; n++) {
            accg[m][n] = (f32x4){0.f, 0.f, 0.f, 0.f};
            accu[m][n] = (f32x4){0.f, 0.f, 0.f, 0.f};
        }

    int arow = wm * 64 + (lane & 15);
    int brow = wn * 32 + (lane & 15);
    int krd = (lane >> 4) * 8;

    for (int k0 = 0; k0 < EDIM; k0 += 32) {
        __syncthreads();              // prior reads done before overwrite
        GL16(gA0, dA0); GL16(gA1, dA1); GL16(gG, dG); GL16(gU, dU);
        gA0 += 32; gA1 += 32; gG += 32; gU += 32;
        __syncthreads();              // loads landed (vmcnt(0) at barrier)
        short8 a[4], g[2], u[2];
#pragma unroll
        for (int m = 0; m < 4; m++) a[m] = *(const short8*)&sA[(arow + m * 16) * 32 + krd];
#pragma unroll
        for (int n = 0; n < 2; n++) {
            g[n] = *(const short8*)&sBg[(brow + n * 16) * 32 + krd];
            u[n] = *(const short8*)&sBu[(brow + n * 16) * 32 + krd];
        }
#pragma unroll
        for (int m = 0; m < 4; m++)
#pragma unroll
            for (int n = 0; n < 2; n++) {
                accg[m][n] = __builtin_amdgcn_mfma_f32_16x16x32_bf16(a[m], g[n], accg[m][n], 0, 0, 0);
                accu[m][n] = __builtin_amdgcn_mfma_f32_16x16x32_bf16(a[m], u[n], accu[m][n], 0, 0, 0);
            }
    }

    int hbase = offsets[e];
#pragma unroll
    for (int m = 0; m < 4; m++) {
        float p[4];
#pragma unroll
        for (int r = 0; r < 4; r++) {
            int pos = m0 + wm * 64 + m * 16 + (lane >> 4) * 4 + r;
            p[r] = (pos < cnt) ? pprob[e * MAXP + pos] : 0.f;
        }
#pragma unroll
        for (int n = 0; n < 2; n++)
#pragma unroll
            for (int r = 0; r < 4; r++) {
                int pos = m0 + wm * 64 + m * 16 + (lane >> 4) * 4 + r;
                if (pos < cnt) {
                    int col = n0 + wn * 32 + n * 16 + (lane & 15);
                    float gv = accg[m][n][r];
                    float uv = accu[m][n][r];
                    float hv = (gv / (1.f + __expf(-gv))) * uv * p[r];
                    hout[(size_t)(hbase + pos) * INTERD + col] = __float2bfloat16(hv);
                }
            }
    }
}

// ---------------- GEMM2: out2[slot] = h[slot] @ wd[e]^T  (128x128, m97 clone) --------
__global__ __launch_bounds__(256) void gemm2_kernel(const bf16* __restrict__ h,
                                                    const bf16* __restrict__ wdb,
                                                    float* __restrict__ out2,
                                                    const int* __restrict__ counts,
                                                    const int* __restrict__ offsets) {
    int e = blockIdx.x >> 5;
    int mt = blockIdx.x & 31;
    int cnt = counts[e];
    int m0 = mt * 128;
    if (m0 >= cnt) return;
    int n0 = blockIdx.y * 128;        // over E (8 tiles)

    __shared__ __align__(16) bf16 sA[128 * 32];
    __shared__ __align__(16) bf16 sB[128 * 32];

    int tid = threadIdx.x;
    int lane = tid & 63;
    int wid = tid >> 6;
    int wm = wid >> 1, wn = wid & 1;  // wave tile: 64 x 64

    int sr = lane >> 2;
    int ch = lane & 3;
    int hbase = offsets[e];
    int ra0 = wid * 16 + sr;
    int ra1 = 64 + ra0;
    const bf16* gA0 = h + (size_t)(hbase + min(m0 + ra0, cnt - 1)) * INTERD + ch * 8;
    const bf16* gA1 = h + (size_t)(hbase + min(m0 + ra1, cnt - 1)) * INTERD + ch * 8;
    const bf16* gB0 = wdb + ((size_t)e * EDIM + n0 + ra0) * INTERD + ch * 8;
    const bf16* gB1 = wdb + ((size_t)e * EDIM + n0 + ra1) * INTERD + ch * 8;
    bf16* dA0 = sA + wid * 512;
    bf16* dA1 = sA + (4 + wid) * 512;
    bf16* dB0 = sB + wid * 512;
    bf16* dB1 = sB + (4 + wid) * 512;

    f32x4 acc[4][4];
#pragma unroll
    for (int m = 0; m < 4; m++)
#pragma unroll
        for (int n = 0; n < 4; n++) acc[m][n] = (f32x4){0.f, 0.f, 0.f, 0.f};

    int arow = wm * 64 + (lane & 15);
    int brow = wn * 64 + (lane & 15);
    int krd = (lane >> 4) * 8;

    for (int k0 = 0; k0 < INTERD; k0 += 32) {
        __syncthreads();
        GL16(gA0, dA0); GL16(gA1, dA1); GL16(gB0, dB0); GL16(gB1, dB1);
        gA0 += 32; gA1 += 32; gB0 += 32; gB1 += 32;
        __syncthreads();
        short8 a[4], b[4];
#pragma unroll
        for (int m = 0; m < 4; m++) a[m] = *(const short8*)&sA[(arow + m * 16) * 32 + krd];
#pragma unroll
        for (int n = 0; n < 4; n++) b[n] = *(const short8*)&sB[(brow + n * 16) * 32 + krd];
#pragma unroll
        for (int m = 0; m < 4; m++)
#pragma unroll
            for (int n = 0; n < 4; n++)
                acc[m][n] = __builtin_amdgcn_mfma_f32_16x16x32_bf16(a[m], b[n], acc[m][n], 0, 0, 0);
    }

#pragma unroll
    for (int m = 0; m < 4; m++)
#pragma unroll
        for (int n = 0; n < 4; n++)
#pragma unroll
            for (int r = 0; r < 4; r++) {
                int pos = m0 + wm * 64 + m * 16 + (lane >> 4) * 4 + r;
                if (pos < cnt) {
                    int col = n0 + wn * 64 + n * 16 + (lane & 15);
                    out2[(size_t)(hbase + pos) * EDIM + col] = acc[m][n][r];
                }
            }
}

// ---------------- combine: y[t] = out2[slot0] + out2[slot1] (probs already folded) ---
__global__ __launch_bounds__(256) void combine_kernel(const float* __restrict__ out2,
                                                      const int* __restrict__ inv,
                                                      const int* __restrict__ offsets,
                                                      float* __restrict__ y) {
    int idx = blockIdx.x * 256 + threadIdx.x;   // NTOK*EDIM/4 threads
    int t = idx >> 8;
    int c = (idx & 255) * 4;
    int a = inv[2 * t], b = inv[2 * t + 1];
    size_t sa = (size_t)(offsets[a >> 16] + (a & 0xFFFF)) * EDIM + c;
    size_t sb = (size_t)(offsets[b >> 16] + (b & 0xFFFF)) * EDIM + c;
    float4 va = *(const float4*)(out2 + sa);
    float4 vb = *(const float4*)(out2 + sb);
    float4 o;
    o.x = va.x + vb.x; o.y = va.y + vb.y; o.z = va.z + vb.z; o.w = va.w + vb.w;
    *(float4*)(y + (size_t)t * EDIM + c) = o;
}

// ---------------- launch ----------------
extern "C" void kernel_launch(void* const* d_in, const int* in_sizes, int n_in,
                              void* d_out, int out_size, void* d_ws, size_t ws_size,
                              hipStream_t stream) {
    const float* x      = (const float*)d_in[0];
    const float* gate_w = (const float*)d_in[1];
    const float* wg     = (const float*)d_in[2];
    const float* wu     = (const float*)d_in[3];
    const float* wd     = (const float*)d_in[4];
    float* y = (float*)d_out;

    char* ws = (char*)d_ws;
    constexpr size_t SZ_XB = (size_t)NTOK * EDIM * 2;          // 8 MB
    constexpr size_t SZ_W  = (size_t)WELEM * 2;                // 23.07 MB
    constexpr size_t SZ_H  = (size_t)NTOK * 2 * INTERD * 2;    // 23.07 MB
    bf16* xb  = (bf16*)ws;
    bf16* wgb = (bf16*)(ws + SZ_XB);
    bf16* wub = (bf16*)(ws + SZ_XB + SZ_W);
    bf16* wdb = (bf16*)(ws + SZ_XB + 2 * SZ_W);
    bf16* h   = (bf16*)(ws + SZ_XB + 3 * SZ_W);
    char* meta = ws + SZ_XB + 3 * SZ_W + SZ_H;
    int*   counts  = (int*)meta;
    int*   offsets = (int*)(meta + 256);
    int*   ptok    = (int*)(meta + 512);
    float* pprob   = (float*)(meta + 512 + (size_t)NEXPT * MAXP * 4);
    int*   inv     = (int*)(meta + 512 + (size_t)NEXPT * MAXP * 8);
    // out2 (8192*1024*4 = 33.6 MB) aliases wgb+wub (46.1 MB), dead after gemm1
    float* out2 = (float*)(ws + SZ_XB);

    hipMemsetAsync(counts, 0, 256, stream);

    cvt4_kernel<<<3584, 256, 0, stream>>>(x, xb, wg, wgb, wu, wub, wd, wdb);
    router_kernel<<<NTOK, 64, 0, stream>>>(x, gate_w, counts, ptok, pprob, inv);
    scan_kernel<<<1, 64, 0, stream>>>(counts, offsets);

    gemm1_kernel<<<dim3(NEXPT * (MAXP / 128), INTERD / 64), 256, 0, stream>>>(
        xb, wgb, wub, h, counts, offsets, ptok, pprob);
    gemm2_kernel<<<dim3(NEXPT * (MAXP / 128), EDIM / 128), 256, 0, stream>>>(
        h, wdb, out2, counts, offsets);
    combine_kernel<<<NTOK * EDIM / 4 / 256, 256, 0, stream>>>(out2, inv, offsets, y);
}

// Round 3
// 378.926 us; speedup vs baseline: 1.4114x; 1.4114x over previous
//
#include <hip/hip_runtime.h>
#include <hip/hip_bf16.h>
#include <stdint.h>

typedef __hip_bfloat16 bf16;
typedef __attribute__((ext_vector_type(8))) short short8;
typedef __attribute__((ext_vector_type(4))) float f32x4;

#define NTOK  4096      // B*T
#define EDIM  1024
#define NEXPT 8
#define INTERD 1408
#define MAXP  4096
#define WELEM (NEXPT * INTERD * EDIM)

// async global->LDS, 16B per lane, dest = wave-uniform base + lane*16
#define GL16(g, l) __builtin_amdgcn_global_load_lds( \
    (const __attribute__((address_space(1))) unsigned int*)(g), \
    (__attribute__((address_space(3))) unsigned int*)(l), 16, 0, 0)

// ---------------- fused fp32 -> bf16 conversion for all 4 tensors ----------------
__global__ __launch_bounds__(256) void cvt4_kernel(const float* __restrict__ x,  bf16* __restrict__ xb,
                                                   const float* __restrict__ wg, bf16* __restrict__ wgb,
                                                   const float* __restrict__ wu, bf16* __restrict__ wub,
                                                   const float* __restrict__ wd, bf16* __restrict__ wdb) {
    const float* src; bf16* dst; int n, b = blockIdx.x, nb;
    if (b < 512)       { src = x;  dst = xb;  n = NTOK * EDIM; nb = 512; }
    else if (b < 1536) { src = wg; dst = wgb; n = WELEM; b -= 512;  nb = 1024; }
    else if (b < 2560) { src = wu; dst = wub; n = WELEM; b -= 1536; nb = 1024; }
    else               { src = wd; dst = wdb; n = WELEM; b -= 2560; nb = 1024; }
    int i = (b * 256 + threadIdx.x) * 4;
    int stride = nb * 256 * 4;
    for (; i < n; i += stride) {
        float4 v = *(const float4*)(src + i);
        ushort4 o; bf16 t;
        t = __float2bfloat16(v.x); o.x = *(unsigned short*)&t;
        t = __float2bfloat16(v.y); o.y = *(unsigned short*)&t;
        t = __float2bfloat16(v.z); o.z = *(unsigned short*)&t;
        t = __float2bfloat16(v.w); o.w = *(unsigned short*)&t;
        *(ushort4*)(dst + i) = o;
    }
}

// ---------------- router: top2 softmax, bucket scatter + inverse map ----------------
__global__ __launch_bounds__(64) void router_kernel(const float* __restrict__ x,
                                                    const float* __restrict__ gw,
                                                    int* __restrict__ counts,
                                                    int* __restrict__ ptok,
                                                    float* __restrict__ pprob,
                                                    int* __restrict__ inv) {
    int t = blockIdx.x;
    int lane = threadIdx.x;
    const float* xr = x + (size_t)t * EDIM;
    double acc[NEXPT];
#pragma unroll
    for (int e = 0; e < NEXPT; e++) acc[e] = 0.0;
    for (int d = lane; d < EDIM; d += 64) {
        float xv = xr[d];
#pragma unroll
        for (int e = 0; e < NEXPT; e++) acc[e] += (double)xv * (double)gw[e * EDIM + d];
    }
#pragma unroll
    for (int off = 32; off >= 1; off >>= 1) {
#pragma unroll
        for (int e = 0; e < NEXPT; e++) acc[e] += __shfl_xor(acc[e], off, 64);
    }
    if (lane == 0) {
        int e0 = 0; double s0 = acc[0];
        for (int e = 1; e < NEXPT; e++) if (acc[e] > s0) { s0 = acc[e]; e0 = e; }
        int e1 = -1; double s1 = -1e300;
        for (int e = 0; e < NEXPT; e++) if (e != e0 && acc[e] > s1) { s1 = acc[e]; e1 = e; }
        float z = __expf((float)(s1 - s0));
        float p0 = 1.f / (1.f + z);
        float p1 = 1.f - p0;
        int pos0 = atomicAdd(&counts[e0], 1);
        ptok[e0 * MAXP + pos0] = t; pprob[e0 * MAXP + pos0] = p0;
        int pos1 = atomicAdd(&counts[e1], 1);
        ptok[e1 * MAXP + pos1] = t; pprob[e1 * MAXP + pos1] = p1;
        inv[2 * t]     = (e0 << 16) | pos0;
        inv[2 * t + 1] = (e1 << 16) | pos1;
    }
}

__global__ void scan_kernel(const int* __restrict__ counts, int* __restrict__ offsets) {
    if (threadIdx.x == 0 && blockIdx.x == 0) {
        int s = 0;
        for (int e = 0; e < NEXPT; e++) { offsets[e] = s; s += counts[e]; }
    }
}

// ======================= GEMM1: h = p * silu(x@wg^T) * (x@wu^T) =======================
// 128 tok x 64 inter, BK=32, double-buffered global_load_lds with source-side swizzle.
// grid: 1-D, blockIdx.x = e + 8*(mt + 16*nt)  -> XCD round-robin keeps expert e on XCD e.
__global__ __launch_bounds__(256) void gemm1_kernel(const bf16* __restrict__ xb,
                                                    const bf16* __restrict__ wgb,
                                                    const bf16* __restrict__ wub,
                                                    bf16* __restrict__ hout,
                                                    const int* __restrict__ counts,
                                                    const int* __restrict__ offsets,
                                                    const int* __restrict__ ptok,
                                                    const float* __restrict__ pprob) {
    int bx = blockIdx.x;
    int e  = bx & 7;
    int mt = (bx >> 3) & 15;
    int nt = bx >> 7;                 // 0..21
    int cnt = counts[e];
    int n0 = nt * 64;
    int hbase = offsets[e];

    __shared__ __align__(16) bf16 sA0[128 * 32], sA1[128 * 32];
    __shared__ __align__(16) bf16 sG0[64 * 32],  sG1[64 * 32];
    __shared__ __align__(16) bf16 sU0[64 * 32],  sU1[64 * 32];

    int tid = threadIdx.x;
    int lane = tid & 63;
    int wid = tid >> 6;
    int wm = wid >> 1, wn = wid & 1;  // wave tile 64 tok x 32 inter

    int sr = lane >> 2;                                  // staged row within 16-row group
    int qg = ((lane & 3) ^ ((lane >> 3) & 3)) * 8;       // swizzled SOURCE chunk (elems)
    int rc = ((lane >> 4) ^ ((lane >> 1) & 3)) * 8;      // swizzled READ chunk (elems)
    int arow = wm * 64 + (lane & 15);
    int brow = wn * 32 + (lane & 15);

    int rb = wid * 16 + sr;
    const bf16* gGb = wgb + ((size_t)e * INTERD + n0 + rb) * EDIM + qg;
    const bf16* gUb = wub + ((size_t)e * INTERD + n0 + rb) * EDIM + qg;

    for (int m0 = mt * 128; m0 < cnt; m0 += 2048) {
        int ta0 = ptok[e * MAXP + min(m0 + rb, cnt - 1)];
        int ta1 = ptok[e * MAXP + min(m0 + 64 + rb, cnt - 1)];
        const bf16* gA0 = xb + (size_t)ta0 * EDIM + qg;
        const bf16* gA1 = xb + (size_t)ta1 * EDIM + qg;
        const bf16* gG = gGb;
        const bf16* gU = gUb;

        f32x4 accg[4][2], accu[4][2];
#pragma unroll
        for (int m = 0; m < 4; m++)
#pragma unroll
            for (int n = 0; n < 2; n++) {
                accg[m][n] = (f32x4){0.f, 0.f, 0.f, 0.f};
                accu[m][n] = (f32x4){0.f, 0.f, 0.f, 0.f};
            }

#define G1_STAGE(dA, dG_, dU_) do { \
        GL16(gA0, (dA) + wid * 512); GL16(gA1, (dA) + 2048 + wid * 512); \
        GL16(gG, (dG_) + wid * 512); GL16(gU, (dU_) + wid * 512); \
        gA0 += 32; gA1 += 32; gG += 32; gU += 32; } while (0)

#define G1_COMP(pA, pG, pU) do { \
        short8 a_[4], g_[2], u_[2]; \
        _Pragma("unroll") for (int m = 0; m < 4; m++) \
            a_[m] = *(const short8*)&(pA)[(arow + m * 16) * 32 + rc]; \
        _Pragma("unroll") for (int n = 0; n < 2; n++) { \
            g_[n] = *(const short8*)&(pG)[(brow + n * 16) * 32 + rc]; \
            u_[n] = *(const short8*)&(pU)[(brow + n * 16) * 32 + rc]; } \
        _Pragma("unroll") for (int m = 0; m < 4; m++) \
        _Pragma("unroll") for (int n = 0; n < 2; n++) { \
            accg[m][n] = __builtin_amdgcn_mfma_f32_16x16x32_bf16(a_[m], g_[n], accg[m][n], 0, 0, 0); \
            accu[m][n] = __builtin_amdgcn_mfma_f32_16x16x32_bf16(a_[m], u_[n], accu[m][n], 0, 0, 0); } } while (0)

        G1_STAGE(sA0, sG0, sU0);          // prologue: tile 0 -> buf0
        __syncthreads();                  // drains vmcnt(0)
        for (int k = 0; k < 32; k += 2) {
            G1_STAGE(sA1, sG1, sU1);      // tile k+1 in flight during compute of k
            G1_COMP(sA0, sG0, sU0);
            __syncthreads();
            if (k + 2 < 32) G1_STAGE(sA0, sG0, sU0);
            G1_COMP(sA1, sG1, sU1);
            __syncthreads();
        }
#undef G1_STAGE
#undef G1_COMP

#pragma unroll
        for (int m = 0; m < 4; m++)
#pragma unroll
            for (int n = 0; n < 2; n++)
#pragma unroll
                for (int r = 0; r < 4; r++) {
                    int pos = m0 + wm * 64 + m * 16 + (lane >> 4) * 4 + r;
                    if (pos < cnt) {
                        int col = n0 + wn * 32 + n * 16 + (lane & 15);
                        float p = pprob[e * MAXP + pos];
                        float gv = accg[m][n][r];
                        float uv = accu[m][n][r];
                        float hv = (gv / (1.f + __expf(-gv))) * uv * p;
                        hout[(size_t)(hbase + pos) * INTERD + col] = __float2bfloat16(hv);
                    }
                }
    }
}

// ======================= GEMM2: out2[slot] = h[slot] @ wd[e]^T =======================
// 128 x 128, BK=32 (44 steps), same double-buffer + swizzle structure.
// grid: blockIdx.x = e + 8*(mt + 16*nt), nt in [0,8)
__global__ __launch_bounds__(256) void gemm2_kernel(const bf16* __restrict__ h,
                                                    const bf16* __restrict__ wdb,
                                                    float* __restrict__ out2,
                                                    const int* __restrict__ counts,
                                                    const int* __restrict__ offsets) {
    int bx = blockIdx.x;
    int e  = bx & 7;
    int mt = (bx >> 3) & 15;
    int nt = bx >> 7;                 // 0..7
    int cnt = counts[e];
    int n0 = nt * 128;
    int hbase = offsets[e];

    __shared__ __align__(16) bf16 sA0[128 * 32], sA1[128 * 32];
    __shared__ __align__(16) bf16 sB0[128 * 32], sB1[128 * 32];

    int tid = threadIdx.x;
    int lane = tid & 63;
    int wid = tid >> 6;
    int wm = wid >> 1, wn = wid & 1;  // wave tile 64 x 64

    int sr = lane >> 2;
    int qg = ((lane & 3) ^ ((lane >> 3) & 3)) * 8;
    int rc = ((lane >> 4) ^ ((lane >> 1) & 3)) * 8;
    int arow = wm * 64 + (lane & 15);
    int brow = wn * 64 + (lane & 15);

    int rb = wid * 16 + sr;
    const bf16* gB0b = wdb + ((size_t)e * EDIM + n0 + rb) * INTERD + qg;
    const bf16* gB1b = wdb + ((size_t)e * EDIM + n0 + 64 + rb) * INTERD + qg;

    for (int m0 = mt * 128; m0 < cnt; m0 += 2048) {
        const bf16* gA0 = h + (size_t)(hbase + min(m0 + rb, cnt - 1)) * INTERD + qg;
        const bf16* gA1 = h + (size_t)(hbase + min(m0 + 64 + rb, cnt - 1)) * INTERD + qg;
        const bf16* gB0 = gB0b;
        const bf16* gB1 = gB1b;

        f32x4 acc[4][4];
#pragma unroll
        for (int m = 0; m < 4; m++)
#pragma unroll
            for (int n = 0; n < 4; n++) acc[m][n] = (f32x4){0.f, 0.f, 0.f, 0.f};

#define G2_STAGE(dA, dB) do { \
        GL16(gA0, (dA) + wid * 512); GL16(gA1, (dA) + 2048 + wid * 512); \
        GL16(gB0, (dB) + wid * 512); GL16(gB1, (dB) + 2048 + wid * 512); \
        gA0 += 32; gA1 += 32; gB0 += 32; gB1 += 32; } while (0)

#define G2_COMP(pA, pB) do { \
        short8 a_[4], b_[4]; \
        _Pragma("unroll") for (int m = 0; m < 4; m++) \
            a_[m] = *(const short8*)&(pA)[(arow + m * 16) * 32 + rc]; \
        _Pragma("unroll") for (int n = 0; n < 4; n++) \
            b_[n] = *(const short8*)&(pB)[(brow + n * 16) * 32 + rc]; \
        _Pragma("unroll") for (int m = 0; m < 4; m++) \
        _Pragma("unroll") for (int n = 0; n < 4; n++) \
            acc[m][n] = __builtin_amdgcn_mfma_f32_16x16x32_bf16(a_[m], b_[n], acc[m][n], 0, 0, 0); } while (0)

        G2_STAGE(sA0, sB0);
        __syncthreads();
        for (int k = 0; k < 44; k += 2) {
            G2_STAGE(sA1, sB1);
            G2_COMP(sA0, sB0);
            __syncthreads();
            if (k + 2 < 44) G2_STAGE(sA0, sB0);
            G2_COMP(sA1, sB1);
            __syncthreads();
        }
#undef G2_STAGE
#undef G2_COMP

#pragma unroll
        for (int m = 0; m < 4; m++)
#pragma unroll
            for (int n = 0; n < 4; n++)
#pragma unroll
                for (int r = 0; r < 4; r++) {
                    int pos = m0 + wm * 64 + m * 16 + (lane >> 4) * 4 + r;
                    if (pos < cnt) {
                        int col = n0 + wn * 64 + n * 16 + (lane & 15);
                        out2[(size_t)(hbase + pos) * EDIM + col] = acc[m][n][r];
                    }
                }
    }
}

// ---------------- combine: y[t] = out2[slot0] + out2[slot1] (probs already folded) ---
__global__ __launch_bounds__(256) void combine_kernel(const float* __restrict__ out2,
                                                      const int* __restrict__ inv,
                                                      const int* __restrict__ offsets,
                                                      float* __restrict__ y) {
    int idx = blockIdx.x * 256 + threadIdx.x;   // NTOK*EDIM/4 threads
    int t = idx >> 8;
    int c = (idx & 255) * 4;
    int a = inv[2 * t], b = inv[2 * t + 1];
    size_t sa = (size_t)(offsets[a >> 16] + (a & 0xFFFF)) * EDIM + c;
    size_t sb = (size_t)(offsets[b >> 16] + (b & 0xFFFF)) * EDIM + c;
    float4 va = *(const float4*)(out2 + sa);
    float4 vb = *(const float4*)(out2 + sb);
    float4 o;
    o.x = va.x + vb.x; o.y = va.y + vb.y; o.z = va.z + vb.z; o.w = va.w + vb.w;
    *(float4*)(y + (size_t)t * EDIM + c) = o;
}

// ---------------- launch ----------------
extern "C" void kernel_launch(void* const* d_in, const int* in_sizes, int n_in,
                              void* d_out, int out_size, void* d_ws, size_t ws_size,
                              hipStream_t stream) {
    const float* x      = (const float*)d_in[0];
    const float* gate_w = (const float*)d_in[1];
    const float* wg     = (const float*)d_in[2];
    const float* wu     = (const float*)d_in[3];
    const float* wd     = (const float*)d_in[4];
    float* y = (float*)d_out;

    char* ws = (char*)d_ws;
    constexpr size_t SZ_XB = (size_t)NTOK * EDIM * 2;          // 8 MB
    constexpr size_t SZ_W  = (size_t)WELEM * 2;                // 23.07 MB
    constexpr size_t SZ_H  = (size_t)NTOK * 2 * INTERD * 2;    // 23.07 MB
    bf16* xb  = (bf16*)ws;
    bf16* wgb = (bf16*)(ws + SZ_XB);
    bf16* wub = (bf16*)(ws + SZ_XB + SZ_W);
    bf16* wdb = (bf16*)(ws + SZ_XB + 2 * SZ_W);
    bf16* h   = (bf16*)(ws + SZ_XB + 3 * SZ_W);
    char* meta = ws + SZ_XB + 3 * SZ_W + SZ_H;
    int*   counts  = (int*)meta;
    int*   offsets = (int*)(meta + 256);
    int*   ptok    = (int*)(meta + 512);
    float* pprob   = (float*)(meta + 512 + (size_t)NEXPT * MAXP * 4);
    int*   inv     = (int*)(meta + 512 + (size_t)NEXPT * MAXP * 8);
    // out2 (8192*1024*4 = 33.6 MB) aliases wgb+wub (46.1 MB), dead after gemm1
    float* out2 = (float*)(ws + SZ_XB);

    hipMemsetAsync(counts, 0, 256, stream);

    cvt4_kernel<<<3584, 256, 0, stream>>>(x, xb, wg, wgb, wu, wub, wd, wdb);
    router_kernel<<<NTOK, 64, 0, stream>>>(x, gate_w, counts, ptok, pprob, inv);
    scan_kernel<<<1, 64, 0, stream>>>(counts, offsets);

    // blockIdx.x = e + 8*(mt + 16*nt): expert -> XCD affinity via round-robin
    gemm1_kernel<<<NEXPT * 16 * (INTERD / 64), 256, 0, stream>>>(
        xb, wgb, wub, h, counts, offsets, ptok, pprob);
    gemm2_kernel<<<NEXPT * 16 * (EDIM / 128), 256, 0, stream>>>(
        h, wdb, out2, counts, offsets);
    combine_kernel<<<NTOK * EDIM / 4 / 256, 256, 0, stream>>>(out2, inv, offsets, y);
}

// Round 4
// 337.181 us; speedup vs baseline: 1.5861x; 1.1238x over previous
//
#include <hip/hip_runtime.h>
#include <hip/hip_bf16.h>
#include <stdint.h>

typedef __hip_bfloat16 bf16;
typedef __attribute__((ext_vector_type(8))) short short8;
typedef __attribute__((ext_vector_type(4))) float f32x4;

#define NTOK  4096      // B*T
#define EDIM  1024
#define NEXPT 8
#define INTERD 1408
#define MAXP  4096
#define WELEM (NEXPT * INTERD * EDIM)

// async global->LDS, 16B per lane, dest = wave-uniform base + lane*16
#define GL16(g, l) __builtin_amdgcn_global_load_lds( \
    (const __attribute__((address_space(1))) unsigned int*)(g), \
    (__attribute__((address_space(3))) unsigned int*)(l), 16, 0, 0)

#define WAIT_LGKM0() asm volatile("s_waitcnt lgkmcnt(0)" ::: "memory")
#define WAIT_VM(n)   asm volatile("s_waitcnt vmcnt(" #n ")" ::: "memory")
#define BAR()        __builtin_amdgcn_s_barrier()

// ---------------- fused fp32 -> bf16 conversion for all 4 tensors ----------------
__global__ __launch_bounds__(256) void cvt4_kernel(const float* __restrict__ x,  bf16* __restrict__ xb,
                                                   const float* __restrict__ wg, bf16* __restrict__ wgb,
                                                   const float* __restrict__ wu, bf16* __restrict__ wub,
                                                   const float* __restrict__ wd, bf16* __restrict__ wdb) {
    const float* src; bf16* dst; int n, b = blockIdx.x, nb;
    if (b < 512)       { src = x;  dst = xb;  n = NTOK * EDIM; nb = 512; }
    else if (b < 1536) { src = wg; dst = wgb; n = WELEM; b -= 512;  nb = 1024; }
    else if (b < 2560) { src = wu; dst = wub; n = WELEM; b -= 1536; nb = 1024; }
    else               { src = wd; dst = wdb; n = WELEM; b -= 2560; nb = 1024; }
    int i = (b * 256 + threadIdx.x) * 4;
    int stride = nb * 256 * 4;
    for (; i < n; i += stride) {
        float4 v = *(const float4*)(src + i);
        ushort4 o; bf16 t;
        t = __float2bfloat16(v.x); o.x = *(unsigned short*)&t;
        t = __float2bfloat16(v.y); o.y = *(unsigned short*)&t;
        t = __float2bfloat16(v.z); o.z = *(unsigned short*)&t;
        t = __float2bfloat16(v.w); o.w = *(unsigned short*)&t;
        *(ushort4*)(dst + i) = o;
    }
}

// ---------------- router: top2 softmax, bucket scatter + inverse map ----------------
__global__ __launch_bounds__(64) void router_kernel(const float* __restrict__ x,
                                                    const float* __restrict__ gw,
                                                    int* __restrict__ counts,
                                                    int* __restrict__ ptok,
                                                    float* __restrict__ pprob,
                                                    int* __restrict__ inv) {
    int t = blockIdx.x;
    int lane = threadIdx.x;
    const float* xr = x + (size_t)t * EDIM;
    double acc[NEXPT];
#pragma unroll
    for (int e = 0; e < NEXPT; e++) acc[e] = 0.0;
    for (int d = lane; d < EDIM; d += 64) {
        float xv = xr[d];
#pragma unroll
        for (int e = 0; e < NEXPT; e++) acc[e] += (double)xv * (double)gw[e * EDIM + d];
    }
#pragma unroll
    for (int off = 32; off >= 1; off >>= 1) {
#pragma unroll
        for (int e = 0; e < NEXPT; e++) acc[e] += __shfl_xor(acc[e], off, 64);
    }
    if (lane == 0) {
        int e0 = 0; double s0 = acc[0];
        for (int e = 1; e < NEXPT; e++) if (acc[e] > s0) { s0 = acc[e]; e0 = e; }
        int e1 = -1; double s1 = -1e300;
        for (int e = 0; e < NEXPT; e++) if (e != e0 && acc[e] > s1) { s1 = acc[e]; e1 = e; }
        float z = __expf((float)(s1 - s0));
        float p0 = 1.f / (1.f + z);
        float p1 = 1.f - p0;
        int pos0 = atomicAdd(&counts[e0], 1);
        ptok[e0 * MAXP + pos0] = t; pprob[e0 * MAXP + pos0] = p0;
        int pos1 = atomicAdd(&counts[e1], 1);
        ptok[e1 * MAXP + pos1] = t; pprob[e1 * MAXP + pos1] = p1;
        inv[2 * t]     = (e0 << 16) | pos0;
        inv[2 * t + 1] = (e1 << 16) | pos1;
    }
}

__global__ void scan_kernel(const int* __restrict__ counts, int* __restrict__ offsets) {
    if (threadIdx.x == 0 && blockIdx.x == 0) {
        int s = 0;
        for (int e = 0; e < NEXPT; e++) { offsets[e] = s; s += counts[e]; }
    }
}

// ======================= GEMM1: h = p * silu(x@wg^T) * (x@wu^T) =======================
// 128 tok x 64 inter, BK=32, NK=32. 4-deep LDS pipeline, counted vmcnt (T4), raw barriers.
// grid: blockIdx.x = e + 8*(mt + 8*nt); expert->XCD affinity; all blocks useful.
__global__ __launch_bounds__(256) void gemm1_kernel(const bf16* __restrict__ xb,
                                                    const bf16* __restrict__ wgb,
                                                    const bf16* __restrict__ wub,
                                                    bf16* __restrict__ hout,
                                                    const int* __restrict__ counts,
                                                    const int* __restrict__ offsets,
                                                    const int* __restrict__ ptok,
                                                    const float* __restrict__ pprob) {
    int bx = blockIdx.x;
    int e  = bx & 7;
    int mt = (bx >> 3) & 7;
    int nt = bx >> 6;                 // 0..21
    int cnt = counts[e];
    int n0 = nt * 64;
    int hbase = offsets[e];

    // 4 pipeline buffers: A 4x(128x32), G/U 4x(64x32)  = 64 KB total
    __shared__ __align__(16) bf16 sA[4 * 4096];
    __shared__ __align__(16) bf16 sG[4 * 2048];
    __shared__ __align__(16) bf16 sU[4 * 2048];

    int tid = threadIdx.x;
    int lane = tid & 63;
    int wid = tid >> 6;
    int wm = wid >> 1, wn = wid & 1;  // wave tile 64 tok x 32 inter

    int sr = lane >> 2;                                  // staged row in 16-row group
    int qg = ((lane & 3) ^ ((lane >> 3) & 3)) * 8;       // swizzled SOURCE chunk (elems)
    int rc = ((lane >> 4) ^ ((lane >> 1) & 3)) * 8;      // swizzled READ chunk (elems)
    int arow = wm * 64 + (lane & 15);
    int brow = wn * 32 + (lane & 15);

    int rb = wid * 16 + sr;
    const bf16* gG = wgb + ((size_t)e * INTERD + n0 + rb) * EDIM + qg;
    const bf16* gU = wub + ((size_t)e * INTERD + n0 + rb) * EDIM + qg;

    for (int m0 = mt * 128; m0 < cnt; m0 += 1024) {
        WAIT_VM(0);                   // drain prior epilogue stores from vmcnt
        int ta0 = ptok[e * MAXP + min(m0 + rb, cnt - 1)];
        int ta1 = ptok[e * MAXP + min(m0 + 64 + rb, cnt - 1)];
        const bf16* gA0 = xb + (size_t)ta0 * EDIM + qg;
        const bf16* gA1 = xb + (size_t)ta1 * EDIM + qg;

        f32x4 accg[4][2], accu[4][2];
#pragma unroll
        for (int m = 0; m < 4; m++)
#pragma unroll
            for (int n = 0; n < 2; n++) {
                accg[m][n] = (f32x4){0.f, 0.f, 0.f, 0.f};
                accu[m][n] = (f32x4){0.f, 0.f, 0.f, 0.f};
            }

#define G1_STAGE(t) do { int b_ = (t) & 3; \
        GL16(gA0 + (size_t)(t) * 32, sA + b_ * 4096 + wid * 512); \
        GL16(gA1 + (size_t)(t) * 32, sA + b_ * 4096 + 2048 + wid * 512); \
        GL16(gG  + (size_t)(t) * 32, sG + b_ * 2048 + wid * 512); \
        GL16(gU  + (size_t)(t) * 32, sU + b_ * 2048 + wid * 512); } while (0)

#define G1_COMP(t) do { int b_ = (t) & 3; \
        const bf16* pA = sA + b_ * 4096; \
        const bf16* pG = sG + b_ * 2048; \
        const bf16* pU = sU + b_ * 2048; \
        short8 a_[4], g_[2], u_[2]; \
        _Pragma("unroll") for (int m = 0; m < 4; m++) \
            a_[m] = *(const short8*)&pA[(arow + m * 16) * 32 + rc]; \
        _Pragma("unroll") for (int n = 0; n < 2; n++) { \
            g_[n] = *(const short8*)&pG[(brow + n * 16) * 32 + rc]; \
            u_[n] = *(const short8*)&pU[(brow + n * 16) * 32 + rc]; } \
        __builtin_amdgcn_s_setprio(1); \
        _Pragma("unroll") for (int m = 0; m < 4; m++) \
        _Pragma("unroll") for (int n = 0; n < 2; n++) { \
            accg[m][n] = __builtin_amdgcn_mfma_f32_16x16x32_bf16(a_[m], g_[n], accg[m][n], 0, 0, 0); \
            accu[m][n] = __builtin_amdgcn_mfma_f32_16x16x32_bf16(a_[m], u_[n], accu[m][n], 0, 0, 0); } \
        __builtin_amdgcn_s_setprio(0); } while (0)

        G1_STAGE(0); G1_STAGE(1); G1_STAGE(2);   // 12 loads in flight
        for (int k = 0; k < 32; ++k) {
            WAIT_LGKM0();             // my reads of buf[(k+3)&3] (iter k-1) done
            BAR();                    // everyone's reads done -> safe to overwrite
            if (k < 29) {             // uniform branch
                G1_STAGE(k + 3);      // 16 in flight
                WAIT_VM(12);          // oldest 4 (tile k) landed
            } else if (k == 29) { WAIT_VM(8); }
            else if (k == 30)   { WAIT_VM(4); }
            else                { WAIT_VM(0); }
            BAR();                    // tile k visible to all waves
            G1_COMP(k);
        }
#undef G1_STAGE
#undef G1_COMP

#pragma unroll
        for (int m = 0; m < 4; m++)
#pragma unroll
            for (int n = 0; n < 2; n++)
#pragma unroll
                for (int r = 0; r < 4; r++) {
                    int pos = m0 + wm * 64 + m * 16 + (lane >> 4) * 4 + r;
                    if (pos < cnt) {
                        int col = n0 + wn * 32 + n * 16 + (lane & 15);
                        float p = pprob[e * MAXP + pos];
                        float gv = accg[m][n][r];
                        float uv = accu[m][n][r];
                        float hv = (gv / (1.f + __expf(-gv))) * uv * p;
                        hout[(size_t)(hbase + pos) * INTERD + col] = __float2bfloat16(hv);
                    }
                }
    }
}

// ======================= GEMM2: out2[slot] = h[slot] @ wd[e]^T =======================
// 128 x 128, BK=32, NK=44. Same 4-deep counted-vmcnt pipeline.
// grid: blockIdx.x = e + 8*(mt + 8*nt), nt in [0,8)
__global__ __launch_bounds__(256) void gemm2_kernel(const bf16* __restrict__ h,
                                                    const bf16* __restrict__ wdb,
                                                    float* __restrict__ out2,
                                                    const int* __restrict__ counts,
                                                    const int* __restrict__ offsets) {
    int bx = blockIdx.x;
    int e  = bx & 7;
    int mt = (bx >> 3) & 7;
    int nt = bx >> 6;                 // 0..7
    int cnt = counts[e];
    int n0 = nt * 128;
    int hbase = offsets[e];

    __shared__ __align__(16) bf16 sA[4 * 4096];
    __shared__ __align__(16) bf16 sB[4 * 4096];

    int tid = threadIdx.x;
    int lane = tid & 63;
    int wid = tid >> 6;
    int wm = wid >> 1, wn = wid & 1;  // wave tile 64 x 64

    int sr = lane >> 2;
    int qg = ((lane & 3) ^ ((lane >> 3) & 3)) * 8;
    int rc = ((lane >> 4) ^ ((lane >> 1) & 3)) * 8;
    int arow = wm * 64 + (lane & 15);
    int brow = wn * 64 + (lane & 15);

    int rb = wid * 16 + sr;
    const bf16* gB0 = wdb + ((size_t)e * EDIM + n0 + rb) * INTERD + qg;
    const bf16* gB1 = wdb + ((size_t)e * EDIM + n0 + 64 + rb) * INTERD + qg;

    for (int m0 = mt * 128; m0 < cnt; m0 += 1024) {
        WAIT_VM(0);
        const bf16* gA0 = h + (size_t)(hbase + min(m0 + rb, cnt - 1)) * INTERD + qg;
        const bf16* gA1 = h + (size_t)(hbase + min(m0 + 64 + rb, cnt - 1)) * INTERD + qg;

        f32x4 acc[4][4];
#pragma unroll
        for (int m = 0; m < 4; m++)
#pragma unroll
            for (int n = 0; n < 4; n++) acc[m][n] = (f32x4){0.f, 0.f, 0.f, 0.f};

#define G2_STAGE(t) do { int b_ = (t) & 3; \
        GL16(gA0 + (size_t)(t) * 32, sA + b_ * 4096 + wid * 512); \
        GL16(gA1 + (size_t)(t) * 32, sA + b_ * 4096 + 2048 + wid * 512); \
        GL16(gB0 + (size_t)(t) * 32, sB + b_ * 4096 + wid * 512); \
        GL16(gB1 + (size_t)(t) * 32, sB + b_ * 4096 + 2048 + wid * 512); } while (0)

#define G2_COMP(t) do { int b_ = (t) & 3; \
        const bf16* pA = sA + b_ * 4096; \
        const bf16* pB = sB + b_ * 4096; \
        short8 a_[4], b2_[4]; \
        _Pragma("unroll") for (int m = 0; m < 4; m++) \
            a_[m] = *(const short8*)&pA[(arow + m * 16) * 32 + rc]; \
        _Pragma("unroll") for (int n = 0; n < 4; n++) \
            b2_[n] = *(const short8*)&pB[(brow + n * 16) * 32 + rc]; \
        __builtin_amdgcn_s_setprio(1); \
        _Pragma("unroll") for (int m = 0; m < 4; m++) \
        _Pragma("unroll") for (int n = 0; n < 4; n++) \
            acc[m][n] = __builtin_amdgcn_mfma_f32_16x16x32_bf16(a_[m], b2_[n], acc[m][n], 0, 0, 0); \
        __builtin_amdgcn_s_setprio(0); } while (0)

        G2_STAGE(0); G2_STAGE(1); G2_STAGE(2);
        for (int k = 0; k < 44; ++k) {
            WAIT_LGKM0();
            BAR();
            if (k < 41) {
                G2_STAGE(k + 3);
                WAIT_VM(12);
            } else if (k == 41) { WAIT_VM(8); }
            else if (k == 42)   { WAIT_VM(4); }
            else                { WAIT_VM(0); }
            BAR();
            G2_COMP(k);
        }
#undef G2_STAGE
#undef G2_COMP

#pragma unroll
        for (int m = 0; m < 4; m++)
#pragma unroll
            for (int n = 0; n < 4; n++)
#pragma unroll
                for (int r = 0; r < 4; r++) {
                    int pos = m0 + wm * 64 + m * 16 + (lane >> 4) * 4 + r;
                    if (pos < cnt) {
                        int col = n0 + wn * 64 + n * 16 + (lane & 15);
                        out2[(size_t)(hbase + pos) * EDIM + col] = acc[m][n][r];
                    }
                }
    }
}

// ---------------- combine: y[t] = out2[slot0] + out2[slot1] (probs already folded) ---
__global__ __launch_bounds__(256) void combine_kernel(const float* __restrict__ out2,
                                                      const int* __restrict__ inv,
                                                      const int* __restrict__ offsets,
                                                      float* __restrict__ y) {
    int idx = blockIdx.x * 256 + threadIdx.x;   // NTOK*EDIM/4 threads
    int t = idx >> 8;
    int c = (idx & 255) * 4;
    int a = inv[2 * t], b = inv[2 * t + 1];
    size_t sa = (size_t)(offsets[a >> 16] + (a & 0xFFFF)) * EDIM + c;
    size_t sb = (size_t)(offsets[b >> 16] + (b & 0xFFFF)) * EDIM + c;
    float4 va = *(const float4*)(out2 + sa);
    float4 vb = *(const float4*)(out2 + sb);
    float4 o;
    o.x = va.x + vb.x; o.y = va.y + vb.y; o.z = va.z + vb.z; o.w = va.w + vb.w;
    *(float4*)(y + (size_t)t * EDIM + c) = o;
}

// ---------------- launch ----------------
extern "C" void kernel_launch(void* const* d_in, const int* in_sizes, int n_in,
                              void* d_out, int out_size, void* d_ws, size_t ws_size,
                              hipStream_t stream) {
    const float* x      = (const float*)d_in[0];
    const float* gate_w = (const float*)d_in[1];
    const float* wg     = (const float*)d_in[2];
    const float* wu     = (const float*)d_in[3];
    const float* wd     = (const float*)d_in[4];
    float* y = (float*)d_out;

    char* ws = (char*)d_ws;
    constexpr size_t SZ_XB = (size_t)NTOK * EDIM * 2;          // 8 MB
    constexpr size_t SZ_W  = (size_t)WELEM * 2;                // 23.07 MB
    constexpr size_t SZ_H  = (size_t)NTOK * 2 * INTERD * 2;    // 23.07 MB
    bf16* xb  = (bf16*)ws;
    bf16* wgb = (bf16*)(ws + SZ_XB);
    bf16* wub = (bf16*)(ws + SZ_XB + SZ_W);
    bf16* wdb = (bf16*)(ws + SZ_XB + 2 * SZ_W);
    bf16* h   = (bf16*)(ws + SZ_XB + 3 * SZ_W);
    char* meta = ws + SZ_XB + 3 * SZ_W + SZ_H;
    int*   counts  = (int*)meta;
    int*   offsets = (int*)(meta + 256);
    int*   ptok    = (int*)(meta + 512);
    float* pprob   = (float*)(meta + 512 + (size_t)NEXPT * MAXP * 4);
    int*   inv     = (int*)(meta + 512 + (size_t)NEXPT * MAXP * 8);
    // out2 (8192*1024*4 = 33.6 MB) aliases wgb+wub (46.1 MB), dead after gemm1
    float* out2 = (float*)(ws + SZ_XB);

    hipMemsetAsync(counts, 0, 256, stream);

    cvt4_kernel<<<3584, 256, 0, stream>>>(x, xb, wg, wgb, wu, wub, wd, wdb);
    router_kernel<<<NTOK, 64, 0, stream>>>(x, gate_w, counts, ptok, pprob, inv);
    scan_kernel<<<1, 64, 0, stream>>>(counts, offsets);

    // blockIdx.x = e + 8*(mt + 8*nt): expert -> XCD affinity via round-robin
    gemm1_kernel<<<NEXPT * 8 * (INTERD / 64), 256, 0, stream>>>(
        xb, wgb, wub, h, counts, offsets, ptok, pprob);
    gemm2_kernel<<<NEXPT * 8 * (EDIM / 128), 256, 0, stream>>>(
        h, wdb, out2, counts, offsets);
    combine_kernel<<<NTOK * EDIM / 4 / 256, 256, 0, stream>>>(out2, inv, offsets, y);
}

// Round 5
// 314.729 us; speedup vs baseline: 1.6993x; 1.0713x over previous
//
#include <hip/hip_runtime.h>
#include <hip/hip_bf16.h>
#include <stdint.h>

typedef __hip_bfloat16 bf16;
typedef __attribute__((ext_vector_type(8))) short short8;
typedef __attribute__((ext_vector_type(4))) float f32x4;

#define NTOK  4096      // B*T
#define EDIM  1024
#define NEXPT 8
#define INTERD 1408
#define MAXP  4096
#define WELEM (NEXPT * INTERD * EDIM)

// async global->LDS, 16B per lane, dest = wave-uniform base + lane*16
#define GL16(g, l) __builtin_amdgcn_global_load_lds( \
    (const __attribute__((address_space(1))) unsigned int*)(g), \
    (__attribute__((address_space(3))) unsigned int*)(l), 16, 0, 0)

#define WAIT_VM(n)   asm volatile("s_waitcnt vmcnt(" #n ")" ::: "memory")
#define BAR()        __builtin_amdgcn_s_barrier()
#define PRIO(n)      __builtin_amdgcn_s_setprio(n)

// ---------------- fused fp32 -> bf16 conversion for all 4 tensors ----------------
__global__ __launch_bounds__(256) void cvt4_kernel(const float* __restrict__ x,  bf16* __restrict__ xb,
                                                   const float* __restrict__ wg, bf16* __restrict__ wgb,
                                                   const float* __restrict__ wu, bf16* __restrict__ wub,
                                                   const float* __restrict__ wd, bf16* __restrict__ wdb) {
    const float* src; bf16* dst; int n, b = blockIdx.x, nb;
    if (b < 512)       { src = x;  dst = xb;  n = NTOK * EDIM; nb = 512; }
    else if (b < 1536) { src = wg; dst = wgb; n = WELEM; b -= 512;  nb = 1024; }
    else if (b < 2560) { src = wu; dst = wub; n = WELEM; b -= 1536; nb = 1024; }
    else               { src = wd; dst = wdb; n = WELEM; b -= 2560; nb = 1024; }
    int i = (b * 256 + threadIdx.x) * 4;
    int stride = nb * 256 * 4;
    for (; i < n; i += stride) {
        float4 v = *(const float4*)(src + i);
        ushort4 o; bf16 t;
        t = __float2bfloat16(v.x); o.x = *(unsigned short*)&t;
        t = __float2bfloat16(v.y); o.y = *(unsigned short*)&t;
        t = __float2bfloat16(v.z); o.z = *(unsigned short*)&t;
        t = __float2bfloat16(v.w); o.w = *(unsigned short*)&t;
        *(ushort4*)(dst + i) = o;
    }
}

// ---------------- router: top2 softmax, bucket scatter + inverse map ----------------
__global__ __launch_bounds__(64) void router_kernel(const float* __restrict__ x,
                                                    const float* __restrict__ gw,
                                                    int* __restrict__ counts,
                                                    int* __restrict__ ptok,
                                                    float* __restrict__ pprob,
                                                    int* __restrict__ inv) {
    int t = blockIdx.x;
    int lane = threadIdx.x;
    const float* xr = x + (size_t)t * EDIM;
    double acc[NEXPT];
#pragma unroll
    for (int e = 0; e < NEXPT; e++) acc[e] = 0.0;
    for (int d = lane; d < EDIM; d += 64) {
        float xv = xr[d];
#pragma unroll
        for (int e = 0; e < NEXPT; e++) acc[e] += (double)xv * (double)gw[e * EDIM + d];
    }
#pragma unroll
    for (int off = 32; off >= 1; off >>= 1) {
#pragma unroll
        for (int e = 0; e < NEXPT; e++) acc[e] += __shfl_xor(acc[e], off, 64);
    }
    if (lane == 0) {
        int e0 = 0; double s0 = acc[0];
        for (int e = 1; e < NEXPT; e++) if (acc[e] > s0) { s0 = acc[e]; e0 = e; }
        int e1 = -1; double s1 = -1e300;
        for (int e = 0; e < NEXPT; e++) if (e != e0 && acc[e] > s1) { s1 = acc[e]; e1 = e; }
        float z = __expf((float)(s1 - s0));
        float p0 = 1.f / (1.f + z);
        float p1 = 1.f - p0;
        int pos0 = atomicAdd(&counts[e0], 1);
        ptok[e0 * MAXP + pos0] = t; pprob[e0 * MAXP + pos0] = p0;
        int pos1 = atomicAdd(&counts[e1], 1);
        ptok[e1 * MAXP + pos1] = t; pprob[e1 * MAXP + pos1] = p1;
        inv[2 * t]     = (e0 << 16) | pos0;
        inv[2 * t + 1] = (e1 << 16) | pos1;
    }
}

__global__ void scan_kernel(const int* __restrict__ counts, int* __restrict__ offsets) {
    if (threadIdx.x == 0 && blockIdx.x == 0) {
        int s = 0;
        for (int e = 0; e < NEXPT; e++) { offsets[e] = s; s += counts[e]; }
    }
}

// ======================= GEMM1: h = p * silu(x@wg^T) * (x@wu^T) =======================
// Tile 128tok x 128inter (g AND u), BK=64, 16 K-tiles. 8 waves (2M x 4N), wave = 64x32.
// 3-deep LDS pipeline (48KB/tile x 3 = 144KB), 2 phases/K-tile (g-phase, u-phase),
// counted vmcnt(10), T2 both-sides XOR swizzle, setprio around MFMA clusters.
// grid: bx = e + 8*(mt + 8*nt), mt<8, nt<11 -> 704 blocks; expert->XCD affinity.
__global__ __launch_bounds__(512, 2) void gemm1_kernel(const bf16* __restrict__ xb,
                                                       const bf16* __restrict__ wgb,
                                                       const bf16* __restrict__ wub,
                                                       bf16* __restrict__ hout,
                                                       const int* __restrict__ counts,
                                                       const int* __restrict__ offsets,
                                                       const int* __restrict__ ptok,
                                                       const float* __restrict__ pprob) {
    int bx = blockIdx.x;
    int e  = bx & 7;
    int mt = (bx >> 3) & 7;
    int nt = bx >> 6;                 // 0..10
    int cnt = counts[e];
    int n0 = nt * 128;
    int hbase = offsets[e];

    // per buf: A [128][64] @0 (8192 el), G @8192, U @16384; buf = 24576 el = 48KB
    __shared__ __align__(16) bf16 smem[3 * 24576];

    int tid  = threadIdx.x;
    int lane = tid & 63;
    int wid  = tid >> 6;
    int wm   = wid >> 2;              // 0..1  (64-row half)
    int wn   = wid & 3;               // 0..3  (32-col slice)

    int srow = lane >> 3;                      // 0..7
    int qs   = ((lane & 7) ^ srow) * 8;        // swizzled SOURCE elem offset in 64-el row
    int l15  = lane & 15;
    int l4   = lane >> 4;                      // 0..3
    int rx   = lane & 7;                       // read-side XOR
    int rbw  = wid * 8 + srow;                 // staging row 0..63

    const bf16* gGr = wgb + ((size_t)e * INTERD + n0) * EDIM;
    const bf16* gUr = wub + ((size_t)e * INTERD + n0) * EDIM;

    for (int m0 = mt * 128; m0 < cnt; m0 += 1024) {
        WAIT_VM(0);                   // clean vmcnt (prior stores/loads drained)
        int tk0 = ptok[e * MAXP + min(m0 + rbw, cnt - 1)];
        int tk1 = ptok[e * MAXP + min(m0 + 64 + rbw, cnt - 1)];
        const bf16* gA0 = xb + (size_t)tk0 * EDIM + qs;
        const bf16* gA1 = xb + (size_t)tk1 * EDIM + qs;
        const bf16* gG0 = gGr + (size_t)rbw * EDIM + qs;
        const bf16* gG1 = gGr + (size_t)(64 + rbw) * EDIM + qs;
        const bf16* gU0 = gUr + (size_t)rbw * EDIM + qs;
        const bf16* gU1 = gUr + (size_t)(64 + rbw) * EDIM + qs;

        f32x4 accg[4][2], accu[4][2];
#pragma unroll
        for (int m = 0; m < 4; m++)
#pragma unroll
            for (int n = 0; n < 2; n++) {
                accg[m][n] = (f32x4){0.f, 0.f, 0.f, 0.f};
                accu[m][n] = (f32x4){0.f, 0.f, 0.f, 0.f};
            }

#define SB1(t) (smem + ((t) % 3) * 24576)
#define G1_STAGE_AG(t) do { bf16* sb_ = SB1(t); int ko_ = (t) * 64; \
        GL16(gA0 + ko_, sb_ + (wid * 8) * 64); \
        GL16(gA1 + ko_, sb_ + (64 + wid * 8) * 64); \
        GL16(gG0 + ko_, sb_ + 8192 + (wid * 8) * 64); \
        GL16(gG1 + ko_, sb_ + 8192 + (64 + wid * 8) * 64); } while (0)
#define G1_STAGE_U(t) do { bf16* sb_ = SB1(t); int ko_ = (t) * 64; \
        GL16(gU0 + ko_, sb_ + 16384 + (wid * 8) * 64); \
        GL16(gU1 + ko_, sb_ + 16384 + (64 + wid * 8) * 64); } while (0)

        // prologue: tiles 0 and 1 fully staged (12 loads in flight)
        G1_STAGE_AG(0); G1_STAGE_U(0);
        G1_STAGE_AG(1); G1_STAGE_U(1);

        for (int t = 0; t < 16; ++t) {
            const bf16* sb = SB1(t);
            // ---- phase 1 (g) ----
            if (t + 2 < 16)       { G1_STAGE_AG(t + 2); WAIT_VM(10); }
            else if (t + 2 == 16) { WAIT_VM(6); }
            else                  { WAIT_VM(0); }
            BAR();                                 // tile t landed for all waves
            short8 a_[4][2], gf[2][2];
#pragma unroll
            for (int m = 0; m < 4; m++)
#pragma unroll
                for (int kh = 0; kh < 2; kh++)
                    a_[m][kh] = *(const short8*)&sb[(wm * 64 + m * 16 + l15) * 64 +
                                                    (((kh * 4 + l4) ^ rx) * 8)];
#pragma unroll
            for (int n = 0; n < 2; n++)
#pragma unroll
                for (int kh = 0; kh < 2; kh++)
                    gf[n][kh] = *(const short8*)&sb[8192 + (wn * 32 + n * 16 + l15) * 64 +
                                                    (((kh * 4 + l4) ^ rx) * 8)];
            PRIO(1);
#pragma unroll
            for (int m = 0; m < 4; m++)
#pragma unroll
                for (int n = 0; n < 2; n++)
#pragma unroll
                    for (int kh = 0; kh < 2; kh++)
                        accg[m][n] = __builtin_amdgcn_mfma_f32_16x16x32_bf16(
                            a_[m][kh], gf[n][kh], accg[m][n], 0, 0, 0);
            PRIO(0);
            BAR();
            // ---- phase 2 (u) ----
            if (t + 2 < 16) G1_STAGE_U(t + 2);
            short8 uf[2][2];
#pragma unroll
            for (int n = 0; n < 2; n++)
#pragma unroll
                for (int kh = 0; kh < 2; kh++)
                    uf[n][kh] = *(const short8*)&sb[16384 + (wn * 32 + n * 16 + l15) * 64 +
                                                    (((kh * 4 + l4) ^ rx) * 8)];
            PRIO(1);
#pragma unroll
            for (int m = 0; m < 4; m++)
#pragma unroll
                for (int n = 0; n < 2; n++)
#pragma unroll
                    for (int kh = 0; kh < 2; kh++)
                        accu[m][n] = __builtin_amdgcn_mfma_f32_16x16x32_bf16(
                            a_[m][kh], uf[n][kh], accu[m][n], 0, 0, 0);
            PRIO(0);
            BAR();
        }
#undef SB1
#undef G1_STAGE_AG
#undef G1_STAGE_U

        // epilogue: h = silu(g) * u * p
#pragma unroll
        for (int m = 0; m < 4; m++)
#pragma unroll
            for (int n = 0; n < 2; n++)
#pragma unroll
                for (int r = 0; r < 4; r++) {
                    int pos = m0 + wm * 64 + m * 16 + l4 * 4 + r;
                    if (pos < cnt) {
                        int col = n0 + wn * 32 + n * 16 + l15;
                        float p = pprob[e * MAXP + pos];
                        float gv = accg[m][n][r];
                        float uv = accu[m][n][r];
                        float hv = (gv / (1.f + __expf(-gv))) * uv * p;
                        hout[(size_t)(hbase + pos) * INTERD + col] = __float2bfloat16(hv);
                    }
                }
    }
}

// ======================= GEMM2: out2[slot] = h[slot] @ wd[e]^T =======================
// Tile 256slot x 128col, BK=64, 22 K-tiles. 8 waves (2M x 4N), wave = 128x32.
// Same 3-deep pipeline, 2 phases/K-tile (m-half 0, m-half 1), vmcnt(10), swizzle.
// grid: bx = e + 8*(mt + 4*nt), mt<4, nt<8 -> 256 blocks (one full round).
__global__ __launch_bounds__(512, 2) void gemm2_kernel(const bf16* __restrict__ h,
                                                       const bf16* __restrict__ wdb,
                                                       float* __restrict__ out2,
                                                       const int* __restrict__ counts,
                                                       const int* __restrict__ offsets) {
    int bx = blockIdx.x;
    int e  = bx & 7;
    int mt = (bx >> 3) & 3;
    int nt = bx >> 5;                 // 0..7
    int cnt = counts[e];
    int n0 = nt * 128;
    int hbase = offsets[e];

    // per buf: A [256][64] @0 (16384 el), B [128][64] @16384; buf = 24576 el = 48KB
    __shared__ __align__(16) bf16 smem[3 * 24576];

    int tid  = threadIdx.x;
    int lane = tid & 63;
    int wid  = tid >> 6;
    int wm   = wid >> 2;              // 0..1 (128-row half)
    int wn   = wid & 3;               // 0..3 (32-col slice)

    int srow = lane >> 3;
    int qs   = ((lane & 7) ^ srow) * 8;
    int l15  = lane & 15;
    int l4   = lane >> 4;
    int rx   = lane & 7;
    int rbw  = wid * 8 + srow;        // staging row 0..63

    const bf16* gB0 = wdb + ((size_t)e * EDIM + n0 + rbw) * INTERD + qs;
    const bf16* gB1 = wdb + ((size_t)e * EDIM + n0 + 64 + rbw) * INTERD + qs;

    for (int m0 = mt * 256; m0 < cnt; m0 += 1024) {
        WAIT_VM(0);
        const bf16* gA0 = h + (size_t)(hbase + min(m0 + rbw,       cnt - 1)) * INTERD + qs;
        const bf16* gA1 = h + (size_t)(hbase + min(m0 + 64 + rbw,  cnt - 1)) * INTERD + qs;
        const bf16* gA2 = h + (size_t)(hbase + min(m0 + 128 + rbw, cnt - 1)) * INTERD + qs;
        const bf16* gA3 = h + (size_t)(hbase + min(m0 + 192 + rbw, cnt - 1)) * INTERD + qs;

        f32x4 acc[8][2];
#pragma unroll
        for (int m = 0; m < 8; m++)
#pragma unroll
            for (int n = 0; n < 2; n++) acc[m][n] = (f32x4){0.f, 0.f, 0.f, 0.f};

#define SB2(t) (smem + ((t) % 3) * 24576)
#define G2_STAGE_A(t) do { bf16* sb_ = SB2(t); int ko_ = (t) * 64; \
        GL16(gA0 + ko_, sb_ + (wid * 8) * 64); \
        GL16(gA1 + ko_, sb_ + (64 + wid * 8) * 64); \
        GL16(gA2 + ko_, sb_ + (128 + wid * 8) * 64); \
        GL16(gA3 + ko_, sb_ + (192 + wid * 8) * 64); } while (0)
#define G2_STAGE_B(t) do { bf16* sb_ = SB2(t); int ko_ = (t) * 64; \
        GL16(gB0 + ko_, sb_ + 16384 + (wid * 8) * 64); \
        GL16(gB1 + ko_, sb_ + 16384 + (64 + wid * 8) * 64); } while (0)

        G2_STAGE_A(0); G2_STAGE_B(0);
        G2_STAGE_A(1); G2_STAGE_B(1);

        for (int t = 0; t < 22; ++t) {
            const bf16* sb = SB2(t);
            // ---- phase 1 (m-half 0) ----
            if (t + 2 < 22)       { G2_STAGE_A(t + 2); WAIT_VM(10); }
            else if (t + 2 == 22) { WAIT_VM(6); }
            else                  { WAIT_VM(0); }
            BAR();
            short8 a_[4][2], bf_[2][2];
#pragma unroll
            for (int m = 0; m < 4; m++)
#pragma unroll
                for (int kh = 0; kh < 2; kh++)
                    a_[m][kh] = *(const short8*)&sb[(wm * 128 + m * 16 + l15) * 64 +
                                                    (((kh * 4 + l4) ^ rx) * 8)];
#pragma unroll
            for (int n = 0; n < 2; n++)
#pragma unroll
                for (int kh = 0; kh < 2; kh++)
                    bf_[n][kh] = *(const short8*)&sb[16384 + (wn * 32 + n * 16 + l15) * 64 +
                                                     (((kh * 4 + l4) ^ rx) * 8)];
            PRIO(1);
#pragma unroll
            for (int m = 0; m < 4; m++)
#pragma unroll
                for (int n = 0; n < 2; n++)
#pragma unroll
                    for (int kh = 0; kh < 2; kh++)
                        acc[m][n] = __builtin_amdgcn_mfma_f32_16x16x32_bf16(
                            a_[m][kh], bf_[n][kh], acc[m][n], 0, 0, 0);
            PRIO(0);
            BAR();
            // ---- phase 2 (m-half 1) ----
            if (t + 2 < 22) G2_STAGE_B(t + 2);
            short8 a2_[4][2];
#pragma unroll
            for (int m = 0; m < 4; m++)
#pragma unroll
                for (int kh = 0; kh < 2; kh++)
                    a2_[m][kh] = *(const short8*)&sb[(wm * 128 + 64 + m * 16 + l15) * 64 +
                                                     (((kh * 4 + l4) ^ rx) * 8)];
            PRIO(1);
#pragma unroll
            for (int m = 0; m < 4; m++)
#pragma unroll
                for (int n = 0; n < 2; n++)
#pragma unroll
                    for (int kh = 0; kh < 2; kh++)
                        acc[4 + m][n] = __builtin_amdgcn_mfma_f32_16x16x32_bf16(
                            a2_[m][kh], bf_[n][kh], acc[4 + m][n], 0, 0, 0);
            PRIO(0);
            BAR();
        }
#undef SB2
#undef G2_STAGE_A
#undef G2_STAGE_B

#pragma unroll
        for (int m = 0; m < 8; m++)
#pragma unroll
            for (int n = 0; n < 2; n++)
#pragma unroll
                for (int r = 0; r < 4; r++) {
                    int pos = m0 + wm * 128 + (m >> 2) * 64 + (m & 3) * 16 + l4 * 4 + r;
                    if (pos < cnt) {
                        int col = n0 + wn * 32 + n * 16 + l15;
                        out2[(size_t)(hbase + pos) * EDIM + col] = acc[m][n][r];
                    }
                }
    }
}

// ---------------- combine: y[t] = out2[slot0] + out2[slot1] (probs already folded) ---
__global__ __launch_bounds__(256) void combine_kernel(const float* __restrict__ out2,
                                                      const int* __restrict__ inv,
                                                      const int* __restrict__ offsets,
                                                      float* __restrict__ y) {
    int idx = blockIdx.x * 256 + threadIdx.x;   // NTOK*EDIM/4 threads
    int t = idx >> 8;
    int c = (idx & 255) * 4;
    int a = inv[2 * t], b = inv[2 * t + 1];
    size_t sa = (size_t)(offsets[a >> 16] + (a & 0xFFFF)) * EDIM + c;
    size_t sb = (size_t)(offsets[b >> 16] + (b & 0xFFFF)) * EDIM + c;
    float4 va = *(const float4*)(out2 + sa);
    float4 vb = *(const float4*)(out2 + sb);
    float4 o;
    o.x = va.x + vb.x; o.y = va.y + vb.y; o.z = va.z + vb.z; o.w = va.w + vb.w;
    *(float4*)(y + (size_t)t * EDIM + c) = o;
}

// ---------------- launch ----------------
extern "C" void kernel_launch(void* const* d_in, const int* in_sizes, int n_in,
                              void* d_out, int out_size, void* d_ws, size_t ws_size,
                              hipStream_t stream) {
    const float* x      = (const float*)d_in[0];
    const float* gate_w = (const float*)d_in[1];
    const float* wg     = (const float*)d_in[2];
    const float* wu     = (const float*)d_in[3];
    const float* wd     = (const float*)d_in[4];
    float* y = (float*)d_out;

    char* ws = (char*)d_ws;
    constexpr size_t SZ_XB = (size_t)NTOK * EDIM * 2;          // 8 MB
    constexpr size_t SZ_W  = (size_t)WELEM * 2;                // 23.07 MB
    constexpr size_t SZ_H  = (size_t)NTOK * 2 * INTERD * 2;    // 23.07 MB
    bf16* xb  = (bf16*)ws;
    bf16* wgb = (bf16*)(ws + SZ_XB);
    bf16* wub = (bf16*)(ws + SZ_XB + SZ_W);
    bf16* wdb = (bf16*)(ws + SZ_XB + 2 * SZ_W);
    bf16* h   = (bf16*)(ws + SZ_XB + 3 * SZ_W);
    char* meta = ws + SZ_XB + 3 * SZ_W + SZ_H;
    int*   counts  = (int*)meta;
    int*   offsets = (int*)(meta + 256);
    int*   ptok    = (int*)(meta + 512);
    float* pprob   = (float*)(meta + 512 + (size_t)NEXPT * MAXP * 4);
    int*   inv     = (int*)(meta + 512 + (size_t)NEXPT * MAXP * 8);
    // out2 (8192*1024*4 = 33.6 MB) aliases wgb+wub (46.1 MB), dead after gemm1
    float* out2 = (float*)(ws + SZ_XB);

    hipMemsetAsync(counts, 0, 256, stream);

    cvt4_kernel<<<3584, 256, 0, stream>>>(x, xb, wg, wgb, wu, wub, wd, wdb);
    router_kernel<<<NTOK, 64, 0, stream>>>(x, gate_w, counts, ptok, pprob, inv);
    scan_kernel<<<1, 64, 0, stream>>>(counts, offsets);

    // bx = e + 8*(mt + 8*nt): expert -> XCD affinity via round-robin
    gemm1_kernel<<<NEXPT * 8 * (INTERD / 128), 512, 0, stream>>>(
        xb, wgb, wub, h, counts, offsets, ptok, pprob);
    // bx = e + 8*(mt + 4*nt): 256 blocks, one full round
    gemm2_kernel<<<NEXPT * 4 * (EDIM / 128), 512, 0, stream>>>(
        h, wdb, out2, counts, offsets);
    combine_kernel<<<NTOK * EDIM / 4 / 256, 256, 0, stream>>>(out2, inv, offsets, y);
}